// Round 12
// baseline (163.834 us; speedup 1.0000x reference)
//
#include <hip/hip_runtime.h>
#include <hip/hip_bf16.h>
#include <cstdint>

typedef __attribute__((ext_vector_type(8))) short short8;
typedef __attribute__((ext_vector_type(4))) float f32x4;

typedef const unsigned int __attribute__((address_space(1)))* gas_ptr;
typedef unsigned int __attribute__((address_space(3)))* las_ptr;

__device__ static inline void async16(const void* g, void* l) {
  __builtin_amdgcn_global_load_lds((gas_ptr)g, (las_ptr)l, 16, 0, 0);
}

__device__ static inline unsigned short f2bf(float f) {
  union { float f; uint32_t u; } v; v.f = f;
  uint32_t u = v.u;
  uint32_t r = (u + 0x7FFFu + ((u >> 16) & 1u)) >> 16;
  return (unsigned short)r;
}
__device__ static inline float bf2f(unsigned short s) {
  union { uint32_t u; float f; } v; v.u = ((uint32_t)s) << 16; return v.f;
}

__device__ static inline float wave_sum(float v) {
  v += __shfl_xor(v, 1);  v += __shfl_xor(v, 2);  v += __shfl_xor(v, 4);
  v += __shfl_xor(v, 8);  v += __shfl_xor(v, 16); v += __shfl_xor(v, 32);
  return v;
}

#define SBAR __builtin_amdgcn_sched_barrier(0)

// ---------------- fused preamble: xext(+rownorm) | trig tables | wnorm x2 ----------------
// grid 5440: [0,4352) xext, [4352,4416) trig, [4416,5184) wnorm Wq, [5184,5440) wnorm Wo
__global__ __launch_bounds__(256) void k_prep(const float* __restrict__ x,
    const float* __restrict__ sink, const float* __restrict__ re,
    const float* __restrict__ w_qkv, const float* __restrict__ w_out,
    unsigned short* __restrict__ Xe, unsigned short* __restrict__ Wq,
    unsigned short* __restrict__ Wo,
    float* __restrict__ ctT, float* __restrict__ stT, float* __restrict__ rowsn) {
  __shared__ float red[4];
  const int bid = blockIdx.x;
  const int tid = threadIdx.x, w = tid >> 6, l = tid & 63;
  if (bid < 4352) {
    const int row = bid;
    const int c4 = tid * 4;
    float4 v = make_float4(0.f, 0.f, 0.f, 0.f);
    if (row < 4100) {
      int b = row / 1025, s = row - b * 1025;
      const float* src = (s < 1024) ? (x + ((size_t)(b * 1024 + s)) * 1024 + c4) : (sink + c4);
      v = *(const float4*)src;
    }
    *(ushort4*)(Xe + (size_t)row * 1024 + c4) =
        make_ushort4(f2bf(v.x), f2bf(v.y), f2bf(v.z), f2bf(v.w));
    float ss = v.x * v.x + v.y * v.y + v.z * v.z + v.w * v.w;
    ss = wave_sum(ss);
    if (l == 0) red[w] = ss;
    __syncthreads();
    if (tid == 0) rowsn[row] = (row < 4100) ? sqrtf(red[0] + red[1] + red[2] + red[3]) : 0.f;
  } else if (bid < 4416) {
    int i = (bid - 4352) * 256 + tid;     // 0..16383
    int s = i >> 4, r2 = i & 15;
    float f = re[s * 32 + r2];
    ctT[r2 * 1024 + s] = cosf(f);
    stT[r2 * 1024 + s] = sinf(f);
  } else {
    const float* W; unsigned short* E; int row;
    if (bid < 5184) { W = w_qkv; E = Wq; row = (bid - 4416) * 4 + w; }
    else            { W = w_out; E = Wo; row = (bid - 5184) * 4 + w; }
    const float* wr = W + (size_t)row * 1024;
    float4 v[4];
    float s = 0.f;
    #pragma unroll
    for (int i = 0; i < 4; ++i) {
      v[i] = *(const float4*)(wr + i * 256 + l * 4);
      s += v[i].x * v[i].x + v[i].y * v[i].y + v[i].z * v[i].z + v[i].w * v[i].w;
    }
    s = wave_sum(s);
    float inv = 1.0f / (0.0032f + sqrtf(s));
    unsigned short* er = E + (size_t)row * 1024;
    #pragma unroll
    for (int i = 0; i < 4; ++i) {
      ushort4 o = make_ushort4(f2bf(v[i].x * inv), f2bf(v[i].y * inv),
                               f2bf(v[i].z * inv), f2bf(v[i].w * inv));
      *(ushort4*)(er + i * 256 + l * 4) = o;
    }
  }
}

// ---------------- final norm reduction: scp[bid]=Σrowsn chunk, scp[16+bid]=Σsqrt(rowsq) ----
__global__ __launch_bounds__(256) void k_rownormC(const float* __restrict__ rowsqp,
    const float* __restrict__ rowsn, float* __restrict__ scp) {
  __shared__ float red[4];
  const int bid = blockIdx.x, t = threadIdx.x, w = t >> 6, l = t & 63;
  const int row = bid * 256 + t;
  const float4* rp = (const float4*)(rowsqp + (size_t)row * 16);
  float4 a = rp[0], b = rp[1], c = rp[2], d = rp[3];
  float s = a.x + a.y + a.z + a.w + b.x + b.y + b.z + b.w +
            c.x + c.y + c.z + c.w + d.x + d.y + d.z + d.w;
  float v = sqrtf(s);
  v = wave_sum(v);
  if (l == 0) red[w] = v;
  __syncthreads();
  if (t == 0) scp[16 + bid] = red[0] + red[1] + red[2] + red[3];
  float u = 0.f;
  for (int k = t; k < 272; k += 256) u += rowsn[bid * 272 + k];
  u = wave_sum(u);
  __syncthreads();
  if (l == 0) red[w] = u;
  __syncthreads();
  if (t == 0) scp[bid] = red[0] + red[1] + red[2] + red[3];
}

// ---------------- unified GEMM: A via LDS (swizzled), B DIRECT global->VGPR ----------
// C[M][N] = A[M][K] * B[N][K]^T.  B-panel is L2-hot (reused by all tm-blocks).
// EPI=1: BM=128, fused QKV epilogue (RoPE+norm+Vt). EPI=0: BM=64, f32 C scaled by ratio.
template<int EPI>
__global__ __launch_bounds__(256, 4) void k_gemm128(
    const unsigned short* __restrict__ A, const unsigned short* __restrict__ B,
    float* __restrict__ C, int N, int K, int ntn,
    unsigned short* __restrict__ Qh, unsigned short* __restrict__ Kh,
    unsigned short* __restrict__ Vt,
    const float* __restrict__ ctT, const float* __restrict__ stT,
    const float* __restrict__ scp) {
  constexpr int BM = EPI ? 128 : 64;
  constexpr int MI = BM / 32;                 // acc m-fragments per wave
  constexpr int SMEM_ELEMS = EPI ? 16384 : 4096;  // EPI=1: 32KB (V-transpose reuse); EPI=0: 8KB
  __shared__ __align__(16) short SMEM[SMEM_ELEMS];
  short* Al = SMEM;                           // BM x 64
  const int t = threadIdx.x, l = t & 63, w = t >> 6;
  const int r = l & 15, g = l >> 4;
  const int wm = w >> 1, wn = w & 1;
  // bijective XCD swizzle (m204)
  const int nwg = gridDim.x;
  const int q = nwg >> 3, rr = nwg & 7;
  const int xcd = blockIdx.x & 7, loc = blockIdx.x >> 3;
  const int wgid = (xcd < rr ? xcd * (q + 1) : rr * (q + 1) + (xcd - rr) * q) + loc;
  const int tm = wgid / ntn, tn = wgid % ntn;
  const size_t am0 = (size_t)tm * BM, bn0 = (size_t)tn * 128;
  const int NT = K >> 6;
  const unsigned short* Bbase = B + (bn0 + wn * 64 + r) * (size_t)K + g * 8;

  f32x4 acc[MI][4] = {};
  for (int tt = 0; tt < NT; ++tt) {
    const int kt = tt * 64;
    __syncthreads();                // previous tile's LDS reads done
    // stage A: LDS[row][ch] = global[row][ch ^ (row&7)]  (linear dest, pre-swizzled src)
    #pragma unroll
    for (int i = 0; i < BM / 32; ++i) {
      int c = i * 256 + t;
      int row = c >> 3, sch = (c & 7) ^ (row & 7);
      async16(A + (am0 + row) * (size_t)K + kt + sch * 8, Al + (i * 256 + w * 64) * 8);
    }
    // B fragments: direct global->VGPR (L2-hot); latency hides under the A-stage drain
    short8 bfr[4][2];
    #pragma unroll
    for (int ni = 0; ni < 4; ++ni)
      #pragma unroll
      for (int ks = 0; ks < 2; ++ks)
        bfr[ni][ks] = *(const short8*)(Bbase + (size_t)(ni * 16) * K + kt + ks * 32);
    __syncthreads();                // drains vmcnt(0): A resident, bfr loaded
    #pragma unroll
    for (int ks = 0; ks < 2; ++ks) {
      short8 af[MI];
      #pragma unroll
      for (int mi = 0; mi < MI; ++mi) {
        const int arow = wm * (MI * 16) + mi * 16 + r;
        af[mi] = *(const short8*)(Al + arow * 64 + (((ks * 4 + g) ^ (arow & 7)) << 3));
      }
      #pragma unroll
      for (int mi = 0; mi < MI; ++mi)
        #pragma unroll
        for (int ni = 0; ni < 4; ++ni)
          acc[mi][ni] = __builtin_amdgcn_mfma_f32_16x16x32_bf16(af[mi], bfr[ni][ks], acc[mi][ni], 0, 0, 0);
    }
  }

  if constexpr (EPI == 0) {
    float num = 0.f, den = 0.f;
    #pragma unroll
    for (int i = 0; i < 16; ++i) { num += scp[i]; den += scp[16 + i]; }
    const float ratio = (num * (1.0f / 4100.0f)) * (4096.0f / den);
    #pragma unroll
    for (int mi = 0; mi < MI; ++mi)
      #pragma unroll
      for (int ni = 0; ni < 4; ++ni)
        #pragma unroll
        for (int j = 0; j < 4; ++j) {
          size_t row = am0 + wm * (MI * 16) + mi * 16 + g * 4 + j;
          size_t col = bn0 + wn * 64 + ni * 16 + r;
          C[row * (size_t)N + col] = acc[mi][ni][j] * ratio;
        }
  } else {
    __syncthreads();   // drain all waves' LDS reads before SMEM reuse
    const int head_global = tn * 2 + wn;   // 0..47, wave-uniform
    const int sel = head_global >> 4;      // 0=q, 1=k, 2=v
    const int h = head_global & 15;
    const int row0 = (int)am0 + wm * 64;

    if (sel < 2) {
      unsigned short* dst = (sel == 0) ? Qh : Kh;
      #pragma unroll
      for (int mi = 0; mi < 4; ++mi) {
        const int rowb = row0 + mi * 16 + g * 4;
        const int b = rowb / 1025;
        const int s0 = rowb - b * 1025;
        float cs[4], sn[4];
        if (s0 + 3 < 1024) {
          float4 c4 = *(const float4*)(ctT + r * 1024 + s0);
          float4 s4 = *(const float4*)(stT + r * 1024 + s0);
          cs[0] = c4.x; cs[1] = c4.y; cs[2] = c4.z; cs[3] = c4.w;
          sn[0] = s4.x; sn[1] = s4.y; sn[2] = s4.z; sn[3] = s4.w;
        } else {
          #pragma unroll
          for (int j = 0; j < 4; ++j) {
            const int rj = rowb + j;
            const int bj = rj / 1025, sj = rj - bj * 1025;
            cs[j] = (sj < 1024) ? ctT[r * 1024 + sj] : 1.f;
            sn[j] = (sj < 1024) ? stT[r * 1024 + sj] : 0.f;
          }
        }
        #pragma unroll
        for (int j = 0; j < 4; ++j) {
          const int row = rowb + j;
          const int b2 = row / 1025, s = row - b2 * 1025;
          const float a0 = acc[mi][0][j], a1 = acc[mi][1][j];
          const float a2 = acc[mi][2][j], a3 = acc[mi][3][j];
          const float r0 = a0 * cs[j] - a1 * sn[j];
          const float r1 = a1 * cs[j] + a0 * sn[j];
          float nrm = r0 * r0 + r1 * r1 + a2 * a2 + a3 * a3;
          nrm += __shfl_xor(nrm, 1); nrm += __shfl_xor(nrm, 2);
          nrm += __shfl_xor(nrm, 4); nrm += __shfl_xor(nrm, 8);
          const float inv = rsqrtf(nrm);
          if (row < 4100) {
            const size_t base = ((size_t)(b2 * 16 + h) * 1088 + s) * 64 + r;
            dst[base]      = f2bf(r0 * inv);
            dst[base + 16] = f2bf(r1 * inv);
            dst[base + 32] = f2bf(a2 * inv);
            dst[base + 48] = f2bf(a3 * inv);
          }
        }
      }
    } else {
      // V: per-wave LDS transpose. vs[d][slot] as ushort4 slots, slot' = slot ^ (d&15).
      short* vs = SMEM + w * 4096;   // 8 KiB per wave: 64 d-rows x 64 shorts
      #pragma unroll
      for (int mi = 0; mi < 4; ++mi) {
        const int slot = mi * 4 + g;
        #pragma unroll
        for (int ni = 0; ni < 4; ++ni) {
          const int d = ni * 16 + r;
          ushort4 pk = make_ushort4(f2bf(acc[mi][ni][0]), f2bf(acc[mi][ni][1]),
                                    f2bf(acc[mi][ni][2]), f2bf(acc[mi][ni][3]));
          *(ushort4*)(vs + d * 64 + ((slot ^ (d & 15)) << 2)) = pk;
        }
      }
      asm volatile("s_waitcnt lgkmcnt(0)" ::: "memory"); SBAR;
      #pragma unroll
      for (int ii = 0; ii < 16; ++ii) {
        const int d = ii * 4 + g;
        ushort4 vv = *(const ushort4*)(vs + d * 64 + (((r ^ (d & 15)) & 15) << 2));
        const int grow = row0 + r * 4;
        const int b0 = grow / 1025, b3 = (grow + 3) / 1025;
        if (b0 == b3 && grow + 3 < 4100) {
          const int s = grow - b0 * 1025;
          *(ushort4*)(Vt + ((size_t)(b0 * 16 + h) * 64 + d) * 1088 + s) = vv;
        } else {
          unsigned short tmp[4] = {vv.x, vv.y, vv.z, vv.w};
          for (int k2 = 0; k2 < 4; ++k2) {
            const int gr = grow + k2;
            if (gr >= 4100) break;
            const int bb = gr / 1025, ss = gr - bb * 1025;
            Vt[((size_t)(bb * 16 + h) * 64 + d) * 1088 + ss] = tmp[k2];
          }
        }
      }
    }
  }
}

// ---------------- attention: 4 waves share staged K/V across strip pair ----------------
__global__ __launch_bounds__(256) void k_attn(const unsigned short* __restrict__ Qh,
    const unsigned short* __restrict__ Kh, const unsigned short* __restrict__ Vt,
    unsigned short* __restrict__ Hb, float* __restrict__ rowsqp) {
  __shared__ __align__(16) short Kl[2][64 * 64];
  __shared__ __align__(16) short Vl[2][64 * 64];
  __shared__ __align__(16) short Pl[64 * 64];
  const int wid = blockIdx.x;
  const int xcd = wid & 7, jj = wid >> 3;
  const int bh = xcd + 8 * (jj >> 4), pp = jj & 15;
  const int b = bh >> 4, hh = bh & 15;
  const int t = threadIdx.x, l = t & 63, w = t >> 6;
  const int r = l & 15, g = l >> 4;
  const int strip = (w < 2) ? pp : 31 - pp;
  const int qrow0 = strip * 32 + (w & 1) * 16;
  const int myNc = strip / 2 + 1;
  const int NTOT = (31 - pp) / 2 + 2;

  auto stage = [&](int buf, int kt) {
    #pragma unroll
    for (int i = 0; i < 2; ++i) {
      int c = i * 256 + t;
      int row = c >> 3, sch = (c & 7) ^ (row & 7);
      async16(Kh + ((size_t)bh * 1088 + kt * 64 + row) * 64 + sch * 8,
              Kl[buf] + (i * 256 + w * 64) * 8);
      async16(Vt + ((size_t)bh * 64 + row) * 1088 + kt * 64 + sch * 8,
              Vl[buf] + (i * 256 + w * 64) * 8);
    }
  };

  short8 qf[2];
  #pragma unroll
  for (int ks = 0; ks < 2; ++ks)
    qf[ks] = *(const short8*)(Qh + ((size_t)bh * 1088 + qrow0 + r) * 64 + ks * 32 + g * 8);
  f32x4 oacc[4] = {};
  float lsum[4] = {0.f, 0.f, 0.f, 0.f};
  stage(0, 0);
  __syncthreads();
  int cur = 0;
  for (int i = 0; i < NTOT; ++i) {
    const int kt = (i < NTOT - 1) ? i : 16;
    if (i + 1 < NTOT) stage(cur ^ 1, (i + 1 < NTOT - 1) ? (i + 1) : 16);
    const bool active = (i < myNc) || (i == NTOT - 1);   // wave-uniform
    if (active) {
      for (int nc = 0; nc < 4; ++nc) {
        f32x4 sc = {};
        #pragma unroll
        for (int ks = 0; ks < 2; ++ks) {
          const int row = nc * 16 + r;
          const short8 kf = *(const short8*)(Kl[cur] + row * 64 + (((ks * 4 + g) ^ (row & 7)) << 3));
          sc = __builtin_amdgcn_mfma_f32_16x16x32_bf16(qf[ks], kf, sc, 0, 0, 0);
        }
        const int col = kt * 64 + nc * 16 + r;
        #pragma unroll
        for (int j = 0; j < 4; ++j) {
          const int qrow = qrow0 + g * 4 + j;
          const bool valid = (col <= qrow) || (col == 1024);
          float p = valid ? __expf(sc[j]) : 0.0f;
          unsigned short pb = f2bf(p);
          lsum[j] += bf2f(pb);
          const int prow = w * 16 + g * 4 + j;
          const int bir = (nc * 16 + r) * 2;
          char* pd = (char*)Pl + prow * 128 + ((((unsigned)bir >> 4) ^ (prow & 7)) << 4) + (bir & 15);
          *(short*)pd = (short)pb;
        }
      }
      #pragma unroll
      for (int ks = 0; ks < 2; ++ks) {
        const int prow = w * 16 + r;
        const short8 pf = *(const short8*)((char*)Pl + prow * 128 + (((ks * 4 + g) ^ (r & 7)) << 4));
        #pragma unroll
        for (int nd = 0; nd < 4; ++nd) {
          const int vrow = nd * 16 + r;
          const short8 vf = *(const short8*)(Vl[cur] + vrow * 64 + (((ks * 4 + g) ^ (vrow & 7)) << 3));
          oacc[nd] = __builtin_amdgcn_mfma_f32_16x16x32_bf16(pf, vf, oacc[nd], 0, 0, 0);
        }
      }
    }
    __syncthreads();
    cur ^= 1;
  }
  float inv[4];
  #pragma unroll
  for (int j = 0; j < 4; ++j) {
    float v = lsum[j];
    v += __shfl_xor(v, 1); v += __shfl_xor(v, 2);
    v += __shfl_xor(v, 4); v += __shfl_xor(v, 8);
    inv[j] = 1.0f / v;
  }
  #pragma unroll
  for (int j = 0; j < 4; ++j) {
    const int srow = qrow0 + g * 4 + j;
    float sq = 0.f;
    #pragma unroll
    for (int nd = 0; nd < 4; ++nd) {
      const float hv = oacc[nd][j] * inv[j];
      Hb[((size_t)(b * 1024 + srow)) * 1024 + hh * 64 + nd * 16 + r] = f2bf(hv);
      sq += hv * hv;
    }
    sq += __shfl_xor(sq, 1); sq += __shfl_xor(sq, 2);
    sq += __shfl_xor(sq, 4); sq += __shfl_xor(sq, 8);
    if (r == 0) rowsqp[(size_t)(b * 1024 + srow) * 16 + hh] = sq;
  }
}

// ---------------- launcher ----------------
extern "C" void kernel_launch(void* const* d_in, const int* in_sizes, int n_in,
                              void* d_out, int out_size, void* d_ws, size_t ws_size,
                              hipStream_t stream) {
  const float* x     = (const float*)d_in[0];
  const float* re    = (const float*)d_in[1];
  const float* w_qkv = (const float*)d_in[3];
  const float* w_out = (const float*)d_in[4];
  const float* sink  = (const float*)d_in[5];
  char* ws = (char*)d_ws;

  unsigned short* Wq   = (unsigned short*)(ws + 0);          // 3072*1024 bf16
  unsigned short* Wo   = (unsigned short*)(ws + 6291456);    // 1024*1024 bf16
  unsigned short* Xe   = (unsigned short*)(ws + 8388608);    // 4352*1024 bf16
  unsigned short* Hb   = (unsigned short*)(ws + 17301504);   // 4096*1024 bf16
  unsigned short* Qh   = (unsigned short*)(ws + 25690112);   // 64*1088*64 bf16
  unsigned short* Kh   = (unsigned short*)(ws + 34603008);   // 64*1088*64 bf16
  unsigned short* Vt   = (unsigned short*)(ws + 43515904);   // 64*64*1088 bf16
  float*          ctT  = (float*)(ws + 52428800);            // 16*1024 f32
  float*          stT  = (float*)(ws + 52494336);            // 16*1024 f32
  float*          scp  = (float*)(ws + 52559872);            // 32 f32 partials
  float*          rowsn  = (float*)(ws + 52560384);          // 4352 f32
  float*          rowsqp = (float*)(ws + 52577792);          // 4096*16 f32
  float*          out  = (float*)d_out;

  k_prep<<<5440, 256, 0, stream>>>(x, sink, re, w_qkv, w_out, Xe, Wq, Wo, ctT, stT, rowsn);
  k_gemm128<1><<<34 * 24, 256, 0, stream>>>(Xe, Wq, nullptr, 3072, 1024, 24,
                                            Qh, Kh, Vt, ctT, stT, scp);
  k_attn<<<1024, 256, 0, stream>>>(Qh, Kh, Vt, Hb, rowsqp);
  k_rownormC<<<16, 256, 0, stream>>>(rowsqp, rowsn, scp);
  k_gemm128<0><<<64 * 8, 256, 0, stream>>>(Hb, Wo, out, 1024, 1024, 8,
                                           nullptr, nullptr, nullptr, ctT, stT, scp);
}

// Round 13
// 96.922 us; speedup vs baseline: 1.6904x; 1.6904x over previous
//
#include <hip/hip_runtime.h>
#include <hip/hip_bf16.h>
#include <cstdint>

typedef __attribute__((ext_vector_type(8))) short short8;
typedef __attribute__((ext_vector_type(4))) float f32x4;

typedef const unsigned int __attribute__((address_space(1)))* gas_ptr;
typedef unsigned int __attribute__((address_space(3)))* las_ptr;

__device__ static inline void async16(const void* g, void* l) {
  __builtin_amdgcn_global_load_lds((gas_ptr)g, (las_ptr)l, 16, 0, 0);
}

__device__ static inline unsigned short f2bf(float f) {
  union { float f; uint32_t u; } v; v.f = f;
  uint32_t u = v.u;
  uint32_t r = (u + 0x7FFFu + ((u >> 16) & 1u)) >> 16;
  return (unsigned short)r;
}
__device__ static inline float bf2f(unsigned short s) {
  union { uint32_t u; float f; } v; v.u = ((uint32_t)s) << 16; return v.f;
}

__device__ static inline float wave_sum(float v) {
  v += __shfl_xor(v, 1);  v += __shfl_xor(v, 2);  v += __shfl_xor(v, 4);
  v += __shfl_xor(v, 8);  v += __shfl_xor(v, 16); v += __shfl_xor(v, 32);
  return v;
}

#define SBAR __builtin_amdgcn_sched_barrier(0)

// ---------------- fused preamble: xext(+rownorm) | trig tables | wnorm x2 ----------------
// grid 5440: [0,4352) xext, [4352,4416) trig, [4416,5184) wnorm Wq, [5184,5440) wnorm Wo
__global__ __launch_bounds__(256) void k_prep(const float* __restrict__ x,
    const float* __restrict__ sink, const float* __restrict__ re,
    const float* __restrict__ w_qkv, const float* __restrict__ w_out,
    unsigned short* __restrict__ Xe, unsigned short* __restrict__ Wq,
    unsigned short* __restrict__ Wo,
    float* __restrict__ ctT, float* __restrict__ stT, float* __restrict__ rowsn) {
  __shared__ float red[4];
  const int bid = blockIdx.x;
  const int tid = threadIdx.x, w = tid >> 6, l = tid & 63;
  if (bid < 4352) {
    const int row = bid;
    const int c4 = tid * 4;
    float4 v = make_float4(0.f, 0.f, 0.f, 0.f);
    if (row < 4100) {
      int b = row / 1025, s = row - b * 1025;
      const float* src = (s < 1024) ? (x + ((size_t)(b * 1024 + s)) * 1024 + c4) : (sink + c4);
      v = *(const float4*)src;
    }
    *(ushort4*)(Xe + (size_t)row * 1024 + c4) =
        make_ushort4(f2bf(v.x), f2bf(v.y), f2bf(v.z), f2bf(v.w));
    float ss = v.x * v.x + v.y * v.y + v.z * v.z + v.w * v.w;
    ss = wave_sum(ss);
    if (l == 0) red[w] = ss;
    __syncthreads();
    if (tid == 0) rowsn[row] = (row < 4100) ? sqrtf(red[0] + red[1] + red[2] + red[3]) : 0.f;
  } else if (bid < 4416) {
    int i = (bid - 4352) * 256 + tid;     // 0..16383
    int s = i >> 4, r2 = i & 15;
    float f = re[s * 32 + r2];
    ctT[r2 * 1024 + s] = cosf(f);
    stT[r2 * 1024 + s] = sinf(f);
  } else {
    const float* W; unsigned short* E; int row;
    if (bid < 5184) { W = w_qkv; E = Wq; row = (bid - 4416) * 4 + w; }
    else            { W = w_out; E = Wo; row = (bid - 5184) * 4 + w; }
    const float* wr = W + (size_t)row * 1024;
    float4 v[4];
    float s = 0.f;
    #pragma unroll
    for (int i = 0; i < 4; ++i) {
      v[i] = *(const float4*)(wr + i * 256 + l * 4);
      s += v[i].x * v[i].x + v[i].y * v[i].y + v[i].z * v[i].z + v[i].w * v[i].w;
    }
    s = wave_sum(s);
    float inv = 1.0f / (0.0032f + sqrtf(s));
    unsigned short* er = E + (size_t)row * 1024;
    #pragma unroll
    for (int i = 0; i < 4; ++i) {
      ushort4 o = make_ushort4(f2bf(v[i].x * inv), f2bf(v[i].y * inv),
                               f2bf(v[i].z * inv), f2bf(v[i].w * inv));
      *(ushort4*)(er + i * 256 + l * 4) = o;
    }
  }
}

// ---------------- final norm reduction: scp[bid]=Σrowsn chunk, scp[16+bid]=Σsqrt(rowsq) ----
__global__ __launch_bounds__(256) void k_rownormC(const float* __restrict__ rowsqp,
    const float* __restrict__ rowsn, float* __restrict__ scp) {
  __shared__ float red[4];
  const int bid = blockIdx.x, t = threadIdx.x, w = t >> 6, l = t & 63;
  const int row = bid * 256 + t;
  const float4* rp = (const float4*)(rowsqp + (size_t)row * 16);
  float4 a = rp[0], b = rp[1], c = rp[2], d = rp[3];
  float s = a.x + a.y + a.z + a.w + b.x + b.y + b.z + b.w +
            c.x + c.y + c.z + c.w + d.x + d.y + d.z + d.w;
  float v = sqrtf(s);
  v = wave_sum(v);
  if (l == 0) red[w] = v;
  __syncthreads();
  if (t == 0) scp[16 + bid] = red[0] + red[1] + red[2] + red[3];
  float u = 0.f;
  for (int k = t; k < 272; k += 256) u += rowsn[bid * 272 + k];
  u = wave_sum(u);
  __syncthreads();
  if (l == 0) red[w] = u;
  __syncthreads();
  if (t == 0) scp[bid] = red[0] + red[1] + red[2] + red[3];
}

// ---------------- unified GEMM (m97 structure, swizzled, XCD-remapped) ----------
// C[M][N] = A[M][K] * B[N][K]^T.
// EPI=1: BM=128, fused QKV epilogue (RoPE+norm+Vt). EPI=0: BM=64, f32 C scaled by ratio.
template<int EPI>
__global__ __launch_bounds__(256, 4) void k_gemm128(
    const unsigned short* __restrict__ A, const unsigned short* __restrict__ B,
    float* __restrict__ C, int N, int K, int ntn,
    unsigned short* __restrict__ Qh, unsigned short* __restrict__ Kh,
    unsigned short* __restrict__ Vt,
    const float* __restrict__ ctT, const float* __restrict__ stT,
    const float* __restrict__ scp) {
  constexpr int BM = EPI ? 128 : 64;
  constexpr int MI = BM / 32;                 // acc m-fragments per wave
  __shared__ __align__(16) short SMEM[(BM + 128) * 64];
  short* Al = SMEM;                           // BM x 64
  short* Bl = SMEM + BM * 64;                 // 128 x 64
  const int t = threadIdx.x, l = t & 63, w = t >> 6;
  const int r = l & 15, g = l >> 4;
  const int wm = w >> 1, wn = w & 1;
  // bijective XCD swizzle (m204)
  const int nwg = gridDim.x;
  const int q = nwg >> 3, rr = nwg & 7;
  const int xcd = blockIdx.x & 7, loc = blockIdx.x >> 3;
  const int wgid = (xcd < rr ? xcd * (q + 1) : rr * (q + 1) + (xcd - rr) * q) + loc;
  const int tm = wgid / ntn, tn = wgid % ntn;
  const size_t am0 = (size_t)tm * BM, bn0 = (size_t)tn * 128;

  f32x4 acc[MI][4] = {};
  for (int kt = 0; kt < K; kt += 64) {
    __syncthreads();
    // stage: LDS[row][ch] = global[row][ch ^ (row&7)]  (linear dest, pre-swizzled src)
    #pragma unroll
    for (int i = 0; i < BM / 32; ++i) {
      int c = i * 256 + t;
      int row = c >> 3, sch = (c & 7) ^ (row & 7);
      async16(A + (am0 + row) * (size_t)K + kt + sch * 8, Al + (i * 256 + w * 64) * 8);
    }
    #pragma unroll
    for (int i = 0; i < 4; ++i) {
      int c = i * 256 + t;
      int row = c >> 3, sch = (c & 7) ^ (row & 7);
      async16(B + (bn0 + row) * (size_t)K + kt + sch * 8, Bl + (i * 256 + w * 64) * 8);
    }
    __syncthreads();
    #pragma unroll
    for (int ks = 0; ks < 2; ++ks) {
      short8 af[MI], bfr[4];
      #pragma unroll
      for (int mi = 0; mi < MI; ++mi) {
        const int arow = wm * (MI * 16) + mi * 16 + r;
        af[mi] = *(const short8*)(Al + arow * 64 + (((ks * 4 + g) ^ (arow & 7)) << 3));
      }
      #pragma unroll
      for (int ni = 0; ni < 4; ++ni) {
        const int brow = wn * 64 + ni * 16 + r;
        bfr[ni] = *(const short8*)(Bl + brow * 64 + (((ks * 4 + g) ^ (brow & 7)) << 3));
      }
      #pragma unroll
      for (int mi = 0; mi < MI; ++mi)
        #pragma unroll
        for (int ni = 0; ni < 4; ++ni)
          acc[mi][ni] = __builtin_amdgcn_mfma_f32_16x16x32_bf16(af[mi], bfr[ni], acc[mi][ni], 0, 0, 0);
    }
  }

  if constexpr (EPI == 0) {
    float num = 0.f, den = 0.f;
    #pragma unroll
    for (int i = 0; i < 16; ++i) { num += scp[i]; den += scp[16 + i]; }
    const float ratio = (num * (1.0f / 4100.0f)) * (4096.0f / den);
    #pragma unroll
    for (int mi = 0; mi < MI; ++mi)
      #pragma unroll
      for (int ni = 0; ni < 4; ++ni)
        #pragma unroll
        for (int j = 0; j < 4; ++j) {
          size_t row = am0 + wm * (MI * 16) + mi * 16 + g * 4 + j;
          size_t col = bn0 + wn * 64 + ni * 16 + r;
          C[row * (size_t)N + col] = acc[mi][ni][j] * ratio;
        }
  } else {
    __syncthreads();   // drain all waves' LDS reads before SMEM reuse
    const int head_global = tn * 2 + wn;   // 0..47, wave-uniform
    const int sel = head_global >> 4;      // 0=q, 1=k, 2=v
    const int h = head_global & 15;
    const int row0 = (int)am0 + wm * 64;

    if (sel < 2) {
      unsigned short* dst = (sel == 0) ? Qh : Kh;
      #pragma unroll
      for (int mi = 0; mi < 4; ++mi) {
        const int rowb = row0 + mi * 16 + g * 4;
        const int b = rowb / 1025;
        const int s0 = rowb - b * 1025;
        float cs[4], sn[4];
        if (s0 + 3 < 1024) {
          float4 c4 = *(const float4*)(ctT + r * 1024 + s0);
          float4 s4 = *(const float4*)(stT + r * 1024 + s0);
          cs[0] = c4.x; cs[1] = c4.y; cs[2] = c4.z; cs[3] = c4.w;
          sn[0] = s4.x; sn[1] = s4.y; sn[2] = s4.z; sn[3] = s4.w;
        } else {
          #pragma unroll
          for (int j = 0; j < 4; ++j) {
            const int rj = rowb + j;
            const int bj = rj / 1025, sj = rj - bj * 1025;
            cs[j] = (sj < 1024) ? ctT[r * 1024 + sj] : 1.f;
            sn[j] = (sj < 1024) ? stT[r * 1024 + sj] : 0.f;
          }
        }
        #pragma unroll
        for (int j = 0; j < 4; ++j) {
          const int row = rowb + j;
          const int b2 = row / 1025, s = row - b2 * 1025;
          const float a0 = acc[mi][0][j], a1 = acc[mi][1][j];
          const float a2 = acc[mi][2][j], a3 = acc[mi][3][j];
          const float r0 = a0 * cs[j] - a1 * sn[j];
          const float r1 = a1 * cs[j] + a0 * sn[j];
          float nrm = r0 * r0 + r1 * r1 + a2 * a2 + a3 * a3;
          nrm += __shfl_xor(nrm, 1); nrm += __shfl_xor(nrm, 2);
          nrm += __shfl_xor(nrm, 4); nrm += __shfl_xor(nrm, 8);
          const float inv = rsqrtf(nrm);
          if (row < 4100) {
            const size_t base = ((size_t)(b2 * 16 + h) * 1088 + s) * 64 + r;
            dst[base]      = f2bf(r0 * inv);
            dst[base + 16] = f2bf(r1 * inv);
            dst[base + 32] = f2bf(a2 * inv);
            dst[base + 48] = f2bf(a3 * inv);
          }
        }
      }
    } else {
      // V: per-wave LDS transpose. vs[d][slot] as ushort4 slots, slot' = slot ^ (d&15).
      short* vs = SMEM + w * 4096;   // 8 KiB per wave: 64 d-rows x 64 shorts
      #pragma unroll
      for (int mi = 0; mi < 4; ++mi) {
        const int slot = mi * 4 + g;
        #pragma unroll
        for (int ni = 0; ni < 4; ++ni) {
          const int d = ni * 16 + r;
          ushort4 pk = make_ushort4(f2bf(acc[mi][ni][0]), f2bf(acc[mi][ni][1]),
                                    f2bf(acc[mi][ni][2]), f2bf(acc[mi][ni][3]));
          *(ushort4*)(vs + d * 64 + ((slot ^ (d & 15)) << 2)) = pk;
        }
      }
      asm volatile("s_waitcnt lgkmcnt(0)" ::: "memory"); SBAR;
      #pragma unroll
      for (int ii = 0; ii < 16; ++ii) {
        const int d = ii * 4 + g;
        ushort4 vv = *(const ushort4*)(vs + d * 64 + (((r ^ (d & 15)) & 15) << 2));
        const int grow = row0 + r * 4;
        const int b0 = grow / 1025, b3 = (grow + 3) / 1025;
        if (b0 == b3 && grow + 3 < 4100) {
          const int s = grow - b0 * 1025;
          *(ushort4*)(Vt + ((size_t)(b0 * 16 + h) * 64 + d) * 1088 + s) = vv;
        } else {
          unsigned short tmp[4] = {vv.x, vv.y, vv.z, vv.w};
          for (int k2 = 0; k2 < 4; ++k2) {
            const int gr = grow + k2;
            if (gr >= 4100) break;
            const int bb = gr / 1025, ss = gr - bb * 1025;
            Vt[((size_t)(bb * 16 + h) * 64 + d) * 1088 + ss] = tmp[k2];
          }
        }
      }
    }
  }
}

// ---------------- attention: adjacent-strip pairing — all 4 waves active every tile ----
// Block = (bh, p): waves cover q-rows [64p, 64p+64); tiles 0..p + sink (NTOT=p+2).
// High-p (most work) blocks launch first for load balance; XCD swizzle on bh.
__global__ __launch_bounds__(256) void k_attn(const unsigned short* __restrict__ Qh,
    const unsigned short* __restrict__ Kh, const unsigned short* __restrict__ Vt,
    unsigned short* __restrict__ Hb, float* __restrict__ rowsqp) {
  __shared__ __align__(16) short Kl[2][64 * 64];
  __shared__ __align__(16) short Vl[2][64 * 64];
  __shared__ __align__(16) short Pl[64 * 64];
  const int wid = blockIdx.x;
  const int xcd = wid & 7, jj = wid >> 3;          // jj 0..127
  const int bh = xcd + 8 * (jj & 7);               // 0..63
  const int p = 15 - (jj >> 3);                    // 15 first (largest work)
  const int b = bh >> 4, hh = bh & 15;
  const int t = threadIdx.x, l = t & 63, w = t >> 6;
  const int r = l & 15, g = l >> 4;
  const int qrow0 = p * 64 + w * 16;
  const int NTOT = p + 2;                          // causal tiles 0..p, then sink

  auto stage = [&](int buf, int kt) {
    #pragma unroll
    for (int i = 0; i < 2; ++i) {
      int c = i * 256 + t;
      int row = c >> 3, sch = (c & 7) ^ (row & 7);
      async16(Kh + ((size_t)bh * 1088 + kt * 64 + row) * 64 + sch * 8,
              Kl[buf] + (i * 256 + w * 64) * 8);
      async16(Vt + ((size_t)bh * 64 + row) * 1088 + kt * 64 + sch * 8,
              Vl[buf] + (i * 256 + w * 64) * 8);
    }
  };

  short8 qf[2];
  #pragma unroll
  for (int ks = 0; ks < 2; ++ks)
    qf[ks] = *(const short8*)(Qh + ((size_t)bh * 1088 + qrow0 + r) * 64 + ks * 32 + g * 8);
  f32x4 oacc[4] = {};
  float lsum[4] = {0.f, 0.f, 0.f, 0.f};
  stage(0, 0);
  __syncthreads();
  int cur = 0;
  for (int i = 0; i < NTOT; ++i) {
    const int kt = (i < NTOT - 1) ? i : 16;
    if (i + 1 < NTOT) stage(cur ^ 1, (i + 1 < NTOT - 1) ? (i + 1) : 16);
    for (int nc = 0; nc < 4; ++nc) {
      f32x4 sc = {};
      #pragma unroll
      for (int ks = 0; ks < 2; ++ks) {
        const int row = nc * 16 + r;
        const short8 kf = *(const short8*)(Kl[cur] + row * 64 + (((ks * 4 + g) ^ (row & 7)) << 3));
        sc = __builtin_amdgcn_mfma_f32_16x16x32_bf16(qf[ks], kf, sc, 0, 0, 0);
      }
      const int col = kt * 64 + nc * 16 + r;
      #pragma unroll
      for (int j = 0; j < 4; ++j) {
        const int qrow = qrow0 + g * 4 + j;
        const bool valid = (col <= qrow) || (col == 1024);
        float pv = valid ? __expf(sc[j]) : 0.0f;
        unsigned short pb = f2bf(pv);
        lsum[j] += bf2f(pb);
        const int prow = w * 16 + g * 4 + j;
        const int bir = (nc * 16 + r) * 2;
        char* pd = (char*)Pl + prow * 128 + ((((unsigned)bir >> 4) ^ (prow & 7)) << 4) + (bir & 15);
        *(short*)pd = (short)pb;
      }
    }
    #pragma unroll
    for (int ks = 0; ks < 2; ++ks) {
      const int prow = w * 16 + r;
      const short8 pf = *(const short8*)((char*)Pl + prow * 128 + (((ks * 4 + g) ^ (r & 7)) << 4));
      #pragma unroll
      for (int nd = 0; nd < 4; ++nd) {
        const int vrow = nd * 16 + r;
        const short8 vf = *(const short8*)(Vl[cur] + vrow * 64 + (((ks * 4 + g) ^ (vrow & 7)) << 3));
        oacc[nd] = __builtin_amdgcn_mfma_f32_16x16x32_bf16(pf, vf, oacc[nd], 0, 0, 0);
      }
    }
    __syncthreads();
    cur ^= 1;
  }
  float inv[4];
  #pragma unroll
  for (int j = 0; j < 4; ++j) {
    float v = lsum[j];
    v += __shfl_xor(v, 1); v += __shfl_xor(v, 2);
    v += __shfl_xor(v, 4); v += __shfl_xor(v, 8);
    inv[j] = 1.0f / v;
  }
  #pragma unroll
  for (int j = 0; j < 4; ++j) {
    const int srow = qrow0 + g * 4 + j;
    float sq = 0.f;
    #pragma unroll
    for (int nd = 0; nd < 4; ++nd) {
      const float hv = oacc[nd][j] * inv[j];
      Hb[((size_t)(b * 1024 + srow)) * 1024 + hh * 64 + nd * 16 + r] = f2bf(hv);
      sq += hv * hv;
    }
    sq += __shfl_xor(sq, 1); sq += __shfl_xor(sq, 2);
    sq += __shfl_xor(sq, 4); sq += __shfl_xor(sq, 8);
    if (r == 0) rowsqp[(size_t)(b * 1024 + srow) * 16 + hh] = sq;
  }
}

// ---------------- launcher ----------------
extern "C" void kernel_launch(void* const* d_in, const int* in_sizes, int n_in,
                              void* d_out, int out_size, void* d_ws, size_t ws_size,
                              hipStream_t stream) {
  const float* x     = (const float*)d_in[0];
  const float* re    = (const float*)d_in[1];
  const float* w_qkv = (const float*)d_in[3];
  const float* w_out = (const float*)d_in[4];
  const float* sink  = (const float*)d_in[5];
  char* ws = (char*)d_ws;

  unsigned short* Wq   = (unsigned short*)(ws + 0);          // 3072*1024 bf16
  unsigned short* Wo   = (unsigned short*)(ws + 6291456);    // 1024*1024 bf16
  unsigned short* Xe   = (unsigned short*)(ws + 8388608);    // 4352*1024 bf16
  unsigned short* Hb   = (unsigned short*)(ws + 17301504);   // 4096*1024 bf16
  unsigned short* Qh   = (unsigned short*)(ws + 25690112);   // 64*1088*64 bf16
  unsigned short* Kh   = (unsigned short*)(ws + 34603008);   // 64*1088*64 bf16
  unsigned short* Vt   = (unsigned short*)(ws + 43515904);   // 64*64*1088 bf16
  float*          ctT  = (float*)(ws + 52428800);            // 16*1024 f32
  float*          stT  = (float*)(ws + 52494336);            // 16*1024 f32
  float*          scp  = (float*)(ws + 52559872);            // 32 f32 partials
  float*          rowsn  = (float*)(ws + 52560384);          // 4352 f32
  float*          rowsqp = (float*)(ws + 52577792);          // 4096*16 f32
  float*          out  = (float*)d_out;

  k_prep<<<5440, 256, 0, stream>>>(x, sink, re, w_qkv, w_out, Xe, Wq, Wo, ctT, stT, rowsn);
  k_gemm128<1><<<34 * 24, 256, 0, stream>>>(Xe, Wq, nullptr, 3072, 1024, 24,
                                            Qh, Kh, Vt, ctT, stT, scp);
  k_attn<<<1024, 256, 0, stream>>>(Qh, Kh, Vt, Hb, rowsqp);
  k_rownormC<<<16, 256, 0, stream>>>(rowsqp, rowsn, scp);
  k_gemm128<0><<<64 * 8, 256, 0, stream>>>(Hb, Wo, out, 1024, 1024, 8,
                                           nullptr, nullptr, nullptr, ctT, stT, scp);
}